// Round 2
// baseline (1954.851 us; speedup 1.0000x reference)
//
#include <hip/hip_runtime.h>
#include <cstdint>

#define TT  1024
#define BB  32
#define HH  8
#define DD  32
#define YDN 97
#define INN 256

// ---------------------------------------------------------------------------
// Kernel 1: x = softmax(h) over last dim (rows of 32), fp32 in -> fp32 out (ws)
// ---------------------------------------------------------------------------
__global__ __launch_bounds__(256, 1) void softmax_x_kernel(
    const float* __restrict__ hg, float* __restrict__ xg)
{
    const int row  = blockIdx.x * 8 + (threadIdx.x >> 5);
    const int lane = threadIdx.x & 31;
    float v = hg[(size_t)row * DD + lane];
    float m = v;
    #pragma unroll
    for (int s = 16; s > 0; s >>= 1) m = fmaxf(m, __shfl_xor(m, s, 32));
    float ex = __expf(v - m);
    float sm = ex;
    #pragma unroll
    for (int s = 16; s > 0; s >>= 1) sm += __shfl_xor(sm, s, 32);
    xg[(size_t)row * DD + lane] = ex / sm;
}

// ---------------------------------------------------------------------------
// Kernel 2: the recurrent SRWM + fast-weight-memory scan.
// One block per (b,h). All state rows live in registers (transposed layout:
// thread e owns M^T[e][0..31]). LDS only for cross-thread vectors.
// ---------------------------------------------------------------------------
__global__ __launch_bounds__(256, 1) void srwm_fwm_kernel(
    const float* __restrict__ xg,
    const float* __restrict__ Wy_g, const float* __restrict__ Wq_g,
    const float* __restrict__ Wk_g, const float* __restrict__ wb_g,
    const float* __restrict__ sWy_g, const float* __restrict__ sWq_g,
    const float* __restrict__ sWk_g, const float* __restrict__ swb_g,
    const float* __restrict__ F_g,
    float* __restrict__ Og)
{
    const int bh  = blockIdx.x;
    const int b   = bh >> 3;
    const int hh  = bh & 7;
    const int tid = threadIdx.x;

    __shared__ float y_s[YDN];
    __shared__ float q_s[DD];
    __shared__ float k_s[DD];
    __shared__ float qmk_s[DD];
    __shared__ float beta_s[4];
    __shared__ float fq_s[DD];
    __shared__ float fk_s[DD];

    float row[DD];    // this thread's state-matrix row (M^T[e][*])
    float Frow[DD];   // fast-weight row (tids 0..31 only)
    float xv[DD];     // current-step x (block-uniform, per-thread copy)

    int e = -1, mat = -1;
    if (tid < 97)                     { e = tid;       mat = 0; }
    else if (tid < 101)               { e = tid - 97;  mat = 3; }
    else if (tid >= 128 && tid < 160) { e = tid - 128; mat = 1; }
    else if (tid >= 160 && tid < 192) { e = tid - 160; mat = 2; }

    // ---- init: row = (W + state)^T ----
    if (mat == 0) {
        const float* wp = Wy_g  + (size_t)hh * DD * YDN + e;
        const float* sp = sWy_g + (size_t)(b * HH + hh) * DD * YDN + e;
        #pragma unroll
        for (int d = 0; d < DD; d++) row[d] = wp[d * YDN] + sp[d * YDN];
    } else if (mat == 1) {
        const float* wp = Wq_g  + (size_t)hh * DD * DD + e;
        const float* sp = sWq_g + (size_t)(b * HH + hh) * DD * DD + e;
        #pragma unroll
        for (int d = 0; d < DD; d++) row[d] = wp[d * DD] + sp[d * DD];
    } else if (mat == 2) {
        const float* wp = Wk_g  + (size_t)hh * DD * DD + e;
        const float* sp = sWk_g + (size_t)(b * HH + hh) * DD * DD + e;
        #pragma unroll
        for (int d = 0; d < DD; d++) row[d] = wp[d * DD] + sp[d * DD];
    } else if (mat == 3) {
        const float* wp = wb_g  + (size_t)hh * DD * 4 + e;
        const float* sp = swb_g + (size_t)(b * HH + hh) * DD * 4 + e;
        #pragma unroll
        for (int d = 0; d < DD; d++) row[d] = wp[d * 4] + sp[d * 4];
    }
    if (tid < DD) {
        const float* fp = F_g + (size_t)(b * HH + hh) * DD * DD + tid;
        #pragma unroll
        for (int d = 0; d < DD; d++) Frow[d] = fp[d * DD];
    }

    // x for t=0
    {
        const float4* p = (const float4*)(xg + ((size_t)b * HH + hh) * DD);
        #pragma unroll
        for (int g = 0; g < 8; g++) {
            float4 v = p[g];
            xv[4*g+0] = v.x; xv[4*g+1] = v.y; xv[4*g+2] = v.z; xv[4*g+3] = v.w;
        }
    }

    const int wv   = tid >> 6;
    const int lane = tid & 63;

    for (int t = 0; t < TT; t++) {
        __syncthreads();  // barrier 1: prior step's readers of y/q/k done

        // ---- Phase A: pre = x^T M for all rows; softmax(q,k); sigmoid(beta)
        float pre = 0.f;
        if (mat >= 0) {
            #pragma unroll
            for (int d = 0; d < DD; d++) pre += xv[d] * row[d];
        }
        if (wv == 2) {  // whole wave 2: lanes 0-31 = q, 32-63 = k
            float m = pre;
            #pragma unroll
            for (int s = 16; s > 0; s >>= 1) m = fmaxf(m, __shfl_xor(m, s, 32));
            float ex = __expf(pre - m);
            float sm = ex;
            #pragma unroll
            for (int s = 16; s > 0; s >>= 1) sm += __shfl_xor(sm, s, 32);
            float val = ex / sm;
            float other = __shfl_xor(val, 32);   // q lanes get k, k lanes get q
            if (lane < 32) { q_s[lane] = val; qmk_s[lane] = val - other; }
            else           { k_s[lane - 32] = val; }
        } else if (tid < 97) {
            y_s[tid] = pre;
        } else if (tid < 101) {
            beta_s[tid - 97] = 1.f / (1.f + __expf(-pre));
        }
        __syncthreads();  // barrier 2: y/q/k/qmk/beta visible

        // prefetch x(t+1) into registers; latency hides behind phase B/C
        if (t + 1 < TT) {
            const float4* p =
                (const float4*)(xg + (((size_t)(t + 1) * BB + b) * HH + hh) * DD);
            #pragma unroll
            for (int g = 0; g < 8; g++) {
                float4 v = p[g];
                xv[4*g+0] = v.x; xv[4*g+1] = v.y; xv[4*g+2] = v.z; xv[4*g+3] = v.w;
            }
        }

        // ---- Phase B/C fused: dv = (q-k)^T M (row-local), rank-1 update
        if (mat >= 0) {
            float dv = 0.f;
            const float4* qm4 = (const float4*)qmk_s;
            #pragma unroll
            for (int g = 0; g < 8; g++) {
                float4 v = qm4[g];
                dv += v.x * row[4*g+0] + v.y * row[4*g+1]
                    + v.z * row[4*g+2] + v.w * row[4*g+3];
            }
            float bs = beta_s[mat] * dv;
            const float4* k4 = (const float4*)k_s;
            #pragma unroll
            for (int g = 0; g < 8; g++) {
                float4 v = k4[g];
                row[4*g+0] += bs * v.x; row[4*g+1] += bs * v.y;
                row[4*g+2] += bs * v.z; row[4*g+3] += bs * v.w;
            }
        } else if (wv == 3) {  // wave 3: softmax(fq)=y[0:32], softmax(fk)=y[32:64]
            float v = y_s[lane];
            float m = v;
            #pragma unroll
            for (int s = 16; s > 0; s >>= 1) m = fmaxf(m, __shfl_xor(m, s, 32));
            float ex = __expf(v - m);
            float sm = ex;
            #pragma unroll
            for (int s = 16; s > 0; s >>= 1) sm += __shfl_xor(sm, s, 32);
            float val = ex / sm;
            if (lane < 32) fq_s[lane] = val;
            else           fk_s[lane - 32] = val;
        }
        __syncthreads();  // barrier 3: updates done, fq/fk visible

        // ---- Phase D: fast-weight memory (tids 0..31, row-local in F^T)
        if (tid < DD) {
            const float4* fk4 = (const float4*)fk_s;
            const float4* fq4 = (const float4*)fq_s;
            float vold = 0.f;
            #pragma unroll
            for (int g = 0; g < 8; g++) {
                float4 v = fk4[g];
                vold += v.x * Frow[4*g+0] + v.y * Frow[4*g+1]
                      + v.z * Frow[4*g+2] + v.w * Frow[4*g+3];
            }
            float fb    = 1.f / (1.f + __expf(-y_s[96]));
            float delta = fb * (y_s[64 + tid] - vold);
            float outv  = 0.f;
            #pragma unroll
            for (int g = 0; g < 8; g++) {
                float4 kv = fk4[g];
                float4 qv = fq4[g];
                Frow[4*g+0] += delta * kv.x; outv += qv.x * Frow[4*g+0];
                Frow[4*g+1] += delta * kv.y; outv += qv.y * Frow[4*g+1];
                Frow[4*g+2] += delta * kv.z; outv += qv.z * Frow[4*g+2];
                Frow[4*g+3] += delta * kv.w; outv += qv.w * Frow[4*g+3];
            }
            Og[((size_t)t * BB + b) * INN + hh * DD + tid] = outv;
        }
    }
}

// ---------------------------------------------------------------------------
// Kernel 3: out = h + O @ W_out^T   (M=32768, N=K=256), fp32.
// ---------------------------------------------------------------------------
#define GM 128
#define GN 64
#define GK 16

__global__ __launch_bounds__(256, 1) void out_proj_kernel(
    const float* __restrict__ O, const float* __restrict__ W,
    const float* __restrict__ hg, float* __restrict__ outg)
{
    __shared__ float As[GK][GM + 4];
    __shared__ float Bs[GK][GN + 4];
    const int tid = threadIdx.x;
    const int tx  = tid & 15;   // N direction
    const int ty  = tid >> 4;   // M direction
    const int r0  = blockIdx.x * GM;
    const int c0  = blockIdx.y * GN;

    float acc[8][4];
    #pragma unroll
    for (int i = 0; i < 8; i++)
        #pragma unroll
        for (int j = 0; j < 4; j++) acc[i][j] = 0.f;

    const int am  = tid >> 1;         // 0..127
    const int akg = (tid & 1) * 8;    // 0 or 8
    const int bn  = tid >> 2;         // 0..63
    const int bkg = (tid & 3) * 4;    // 0,4,8,12

    for (int k0 = 0; k0 < INN; k0 += GK) {
        float4 a0 = *(const float4*)(O + (size_t)(r0 + am) * INN + k0 + akg);
        float4 a1 = *(const float4*)(O + (size_t)(r0 + am) * INN + k0 + akg + 4);
        float4 w0 = *(const float4*)(W + (size_t)(c0 + bn) * INN + k0 + bkg);
        As[akg+0][am] = a0.x; As[akg+1][am] = a0.y; As[akg+2][am] = a0.z; As[akg+3][am] = a0.w;
        As[akg+4][am] = a1.x; As[akg+5][am] = a1.y; As[akg+6][am] = a1.z; As[akg+7][am] = a1.w;
        Bs[bkg+0][bn] = w0.x; Bs[bkg+1][bn] = w0.y;
        Bs[bkg+2][bn] = w0.z; Bs[bkg+3][bn] = w0.w;
        __syncthreads();
        #pragma unroll
        for (int k = 0; k < GK; k++) {
            float4 av0 = *(const float4*)&As[k][ty * 8];
            float4 av1 = *(const float4*)&As[k][ty * 8 + 4];
            float4 bv  = *(const float4*)&Bs[k][tx * 4];
            float a[8] = {av0.x, av0.y, av0.z, av0.w, av1.x, av1.y, av1.z, av1.w};
            float bb[4] = {bv.x, bv.y, bv.z, bv.w};
            #pragma unroll
            for (int i = 0; i < 8; i++)
                #pragma unroll
                for (int j = 0; j < 4; j++) acc[i][j] += a[i] * bb[j];
        }
        __syncthreads();
    }

    #pragma unroll
    for (int i = 0; i < 8; i++) {
        size_t r = (size_t)(r0 + ty * 8 + i);
        float4 hv = *(const float4*)(hg + r * INN + c0 + tx * 4);
        float4 o;
        o.x = hv.x + acc[i][0];
        o.y = hv.y + acc[i][1];
        o.z = hv.z + acc[i][2];
        o.w = hv.w + acc[i][3];
        *(float4*)(outg + r * INN + c0 + tx * 4) = o;
    }
}

// ---------------------------------------------------------------------------
extern "C" void kernel_launch(void* const* d_in, const int* in_sizes, int n_in,
                              void* d_out, int out_size, void* d_ws, size_t ws_size,
                              hipStream_t stream)
{
    (void)in_sizes; (void)n_in; (void)out_size; (void)ws_size;

    const float* hg   = (const float*)d_in[0];
    const float* Wy   = (const float*)d_in[1];
    const float* Wq   = (const float*)d_in[2];
    const float* Wk   = (const float*)d_in[3];
    const float* wb   = (const float*)d_in[4];
    const float* Wout = (const float*)d_in[5];
    const float* sWy  = (const float*)d_in[6];
    const float* sWq  = (const float*)d_in[7];
    const float* sWk  = (const float*)d_in[8];
    const float* swb  = (const float*)d_in[9];
    const float* Fw   = (const float*)d_in[10];
    float* out = (float*)d_out;

    float* xg = (float*)d_ws;                      // (T,B,H,D) fp32: 33.5 MB
    float* Og = xg + (size_t)TT * BB * INN;        // (T,B,IN)  fp32: 33.5 MB

    softmax_x_kernel<<<TT * BB * HH / 8, 256, 0, stream>>>(hg, xg);
    srwm_fwm_kernel<<<BB * HH, 256, 0, stream>>>(xg, Wy, Wq, Wk, wb,
                                                 sWy, sWq, sWk, swb, Fw, Og);
    out_proj_kernel<<<dim3(TT * BB / GM, INN / GN), 256, 0, stream>>>(Og, Wout, hg, out);
}

// Round 3
// 1107.968 us; speedup vs baseline: 1.7644x; 1.7644x over previous
//
#include <hip/hip_runtime.h>
#include <cstdint>

#define TT  1024
#define BB  32
#define HH  8
#define DD  32
#define YDN 97
#define INN 256

// LDS-only barrier: drains lgkmcnt but leaves global loads/stores in flight
// (avoids __syncthreads()'s s_waitcnt vmcnt(0) which would serialize the
// x-prefetch HBM latency into every step).
__device__ __forceinline__ void bar_lds() {
    asm volatile("s_waitcnt lgkmcnt(0)\n\ts_barrier" ::: "memory");
}

template<int C>
__device__ __forceinline__ float dppf(float x) {
    return __int_as_float(__builtin_amdgcn_update_dpp(
        0, __float_as_int(x), C, 0xF, 0xF, true));
}
__device__ __forceinline__ float swz16(float x) {
    // BitMode xor-16 within each 32-lane group: (16<<10)|31
    return __int_as_float(__builtin_amdgcn_ds_swizzle(__float_as_int(x), 0x401F));
}
// Butterfly reduce over each 32-lane group: 4 DPP (VALU) + 1 ds_swizzle.
__device__ __forceinline__ float red_max32(float v) {
    v = fmaxf(v, dppf<0xB1>(v));    // quad_perm [1,0,3,2]  (xor 1)
    v = fmaxf(v, dppf<0x4E>(v));    // quad_perm [2,3,0,1]  (xor 2)
    v = fmaxf(v, dppf<0x141>(v));   // row_half_mirror      (pairs across quads)
    v = fmaxf(v, dppf<0x140>(v));   // row_mirror           (pairs across octs)
    v = fmaxf(v, swz16(v));         // xor 16
    return v;
}
__device__ __forceinline__ float red_sum32(float v) {
    v += dppf<0xB1>(v);
    v += dppf<0x4E>(v);
    v += dppf<0x141>(v);
    v += dppf<0x140>(v);
    v += swz16(v);
    return v;
}

// ---------------------------------------------------------------------------
// Kernel 1: x = softmax(h) over last dim (rows of 32)
// ---------------------------------------------------------------------------
__global__ __launch_bounds__(256, 1) void softmax_x_kernel(
    const float* __restrict__ hg, float* __restrict__ xg)
{
    const int row  = blockIdx.x * 8 + (threadIdx.x >> 5);
    const int lane = threadIdx.x & 31;
    float v = hg[(size_t)row * DD + lane];
    float m = red_max32(v);
    float ex = __expf(v - m);
    float sm = red_sum32(ex);
    xg[(size_t)row * DD + lane] = ex * __builtin_amdgcn_rcpf(sm);
}

// ---------------------------------------------------------------------------
// Kernel 2: recurrent SRWM + fast-weight memory.
// One block per (b,h). State rows in registers (thread e owns M^T[e][*]).
// Wave roles: w0: Wy rows 0-63 | w1: Wy 64-96, wb 97-100 | w2: Wq, Wk (+q/k
// softmax in-wave) | w3: fq/fk softmax + fast-weight memory (Phase D).
// 2 LDS-only barriers/step; Phase D(t-1) overlaps Phase A(t).
// ---------------------------------------------------------------------------

#define PHASE_D(TPREV)                                                        \
    if (lane < DD) {                                                          \
        const float4* fk4 = (const float4*)fk_s;                              \
        const float4* fq4 = (const float4*)fq_s;                              \
        float v0=0.f,v1=0.f,v2=0.f,v3=0.f;                                    \
        _Pragma("unroll")                                                     \
        for (int g = 0; g < 8; g++) {                                         \
            float4 kv = fk4[g];                                               \
            v0 += kv.x*Frow[g].x; v1 += kv.y*Frow[g].y;                       \
            v2 += kv.z*Frow[g].z; v3 += kv.w*Frow[g].w;                       \
        }                                                                     \
        float vold  = (v0+v1)+(v2+v3);                                        \
        float delta = fb_r * (fv_r - vold);                                   \
        float o0=0.f,o1=0.f,o2=0.f,o3=0.f;                                    \
        _Pragma("unroll")                                                     \
        for (int g = 0; g < 8; g++) {                                         \
            float4 kv = fk4[g];                                               \
            float4 qv = fq4[g];                                               \
            Frow[g].x += delta*kv.x; o0 += qv.x*Frow[g].x;                    \
            Frow[g].y += delta*kv.y; o1 += qv.y*Frow[g].y;                    \
            Frow[g].z += delta*kv.z; o2 += qv.z*Frow[g].z;                    \
            Frow[g].w += delta*kv.w; o3 += qv.w*Frow[g].w;                    \
        }                                                                     \
        Og[((size_t)(TPREV) * (BB*HH) + bh) * DD + lane] = (o0+o1)+(o2+o3);   \
    }

#define STEP(T, XC)                                                           \
  {                                                                           \
    bar_lds();  /* barrier 1 */                                               \
    if (wv == 3) {                                                            \
        if ((T) > 0) { PHASE_D((T)-1) }                                       \
    } else {                                                                  \
        /* Phase A: pre = x . M_row */                                        \
        float pre = 0.f;                                                      \
        if (mat >= 0) {                                                       \
            float p0=0.f,p1=0.f,p2=0.f,p3=0.f;                                \
            _Pragma("unroll")                                                 \
            for (int g = 0; g < 8; g++) {                                     \
                p0 += XC[g].x*row[4*g+0]; p1 += XC[g].y*row[4*g+1];           \
                p2 += XC[g].z*row[4*g+2]; p3 += XC[g].w*row[4*g+3];           \
            }                                                                 \
            pre = (p0+p1)+(p2+p3);                                            \
        }                                                                     \
        if (wv == 2) {  /* lanes 0-31: q softmax, 32-63: k softmax */         \
            float m  = red_max32(pre);                                        \
            float ex = __expf(pre - m);                                       \
            float sm = red_sum32(ex);                                         \
            float val = ex * __builtin_amdgcn_rcpf(sm);                       \
            float other = __shfl_xor(val, 32, 64);                            \
            if (lane < DD) qmk_s[lane] = val - other;                         \
            else           k_s[lane - DD] = val;                              \
        } else if (tid < YDN) {                                               \
            y_s[tid] = pre;                                                   \
        } else if (tid < 101) {                                               \
            beta_s[tid - YDN] = __builtin_amdgcn_rcpf(1.f + __expf(-pre));    \
        }                                                                     \
    }                                                                         \
    bar_lds();  /* barrier 2 */                                               \
    if (wv == 3) {                                                            \
        /* fq/fk softmax + capture fv, fb for Phase D next iteration */       \
        float fpre = y_s[lane];                                               \
        float m  = red_max32(fpre);                                           \
        float ex = __expf(fpre - m);                                          \
        float sm = red_sum32(ex);                                             \
        float val = ex * __builtin_amdgcn_rcpf(sm);                           \
        if (lane < DD) { fq_s[lane] = val; fv_r = y_s[64 + lane]; }           \
        else             fk_s[lane - DD] = val;                               \
        fb_r = __builtin_amdgcn_rcpf(1.f + __expf(-y_s[96]));                 \
    } else {                                                                  \
        /* issue x(t+2) prefetch first: ~1.5 steps to cover HBM latency */    \
        if ((T) + 2 < TT && mat >= 0) {                                       \
            const float4* p =                                                 \
                (const float4*)(xg + ((size_t)((T)+2)*(BB*HH) + bh)*DD);      \
            _Pragma("unroll")                                                 \
            for (int g = 0; g < 8; g++) XC[g] = p[g];                         \
        }                                                                     \
        if (mat >= 0) {                                                       \
            const float4* qm4 = (const float4*)qmk_s;                         \
            const float4* k4  = (const float4*)k_s;                           \
            float bsc = beta_s[mat];                                          \
            float d0=0.f,d1=0.f,d2=0.f,d3=0.f;                                \
            _Pragma("unroll")                                                 \
            for (int g = 0; g < 8; g++) {                                     \
                float4 qv = qm4[g];                                           \
                d0 += qv.x*row[4*g+0]; d1 += qv.y*row[4*g+1];                 \
                d2 += qv.z*row[4*g+2]; d3 += qv.w*row[4*g+3];                 \
            }                                                                 \
            float bs = bsc * ((d0+d1)+(d2+d3));                               \
            _Pragma("unroll")                                                 \
            for (int g = 0; g < 8; g++) {                                     \
                float4 kv = k4[g];                                            \
                row[4*g+0] += bs*kv.x; row[4*g+1] += bs*kv.y;                 \
                row[4*g+2] += bs*kv.z; row[4*g+3] += bs*kv.w;                 \
            }                                                                 \
        }                                                                     \
    }                                                                         \
  }

__global__ __launch_bounds__(256, 1) void srwm_fwm_kernel(
    const float* __restrict__ xg,
    const float* __restrict__ Wy_g, const float* __restrict__ Wq_g,
    const float* __restrict__ Wk_g, const float* __restrict__ wb_g,
    const float* __restrict__ sWy_g, const float* __restrict__ sWq_g,
    const float* __restrict__ sWk_g, const float* __restrict__ swb_g,
    const float* __restrict__ F_g,
    float* __restrict__ Og)
{
    const int bh   = blockIdx.x;
    const int b    = bh >> 3;
    const int hh   = bh & 7;
    const int tid  = threadIdx.x;
    const int wv   = tid >> 6;
    const int lane = tid & 63;

    __shared__ __align__(16) float y_s[YDN];
    __shared__ __align__(16) float k_s[DD];
    __shared__ __align__(16) float qmk_s[DD];
    __shared__ __align__(16) float beta_s[4];
    __shared__ __align__(16) float fq_s[DD];
    __shared__ __align__(16) float fk_s[DD];

    float  row[DD];     // SRWM state row (waves 0-2)
    float4 Frow[8];     // fast-weight row (wave 3, lanes 0-31)
    float4 xA[8], xB[8];
    float  fv_r = 0.f, fb_r = 0.f;

    int e = -1, mat = -1;
    if (tid < 97)                     { e = tid;       mat = 0; }
    else if (tid < 101)               { e = tid - 97;  mat = 3; }
    else if (tid >= 128 && tid < 160) { e = tid - 128; mat = 1; }
    else if (tid >= 160 && tid < 192) { e = tid - 160; mat = 2; }

    // ---- init state rows: row = (W + state)^T ----
    if (mat == 0) {
        const float* wp = Wy_g  + (size_t)hh * DD * YDN + e;
        const float* sp = sWy_g + (size_t)bh * DD * YDN + e;
        #pragma unroll
        for (int d = 0; d < DD; d++) row[d] = wp[d * YDN] + sp[d * YDN];
    } else if (mat == 1) {
        const float* wp = Wq_g  + (size_t)hh * DD * DD + e;
        const float* sp = sWq_g + (size_t)bh * DD * DD + e;
        #pragma unroll
        for (int d = 0; d < DD; d++) row[d] = wp[d * DD] + sp[d * DD];
    } else if (mat == 2) {
        const float* wp = Wk_g  + (size_t)hh * DD * DD + e;
        const float* sp = sWk_g + (size_t)bh * DD * DD + e;
        #pragma unroll
        for (int d = 0; d < DD; d++) row[d] = wp[d * DD] + sp[d * DD];
    } else if (mat == 3) {
        const float* wp = wb_g  + (size_t)hh * DD * 4 + e;
        const float* sp = swb_g + (size_t)bh * DD * 4 + e;
        #pragma unroll
        for (int d = 0; d < DD; d++) row[d] = wp[d * 4] + sp[d * 4];
    }
    if (tid >= 192 && tid < 192 + DD) {   // wave 3 lanes 0-31: F^T rows
        const float* fp = F_g + (size_t)bh * DD * DD + lane;
        #pragma unroll
        for (int g = 0; g < 8; g++)
            Frow[g] = make_float4(fp[(4*g+0)*DD], fp[(4*g+1)*DD],
                                  fp[(4*g+2)*DD], fp[(4*g+3)*DD]);
    }

    // x(0) and x(1) prefetch
    if (mat >= 0) {
        const float4* p0 = (const float4*)(xg + (size_t)bh * DD);
        const float4* p1 = (const float4*)(xg + ((size_t)(BB*HH) + bh) * DD);
        #pragma unroll
        for (int g = 0; g < 8; g++) { xA[g] = p0[g]; xB[g] = p1[g]; }
    }

    for (int t = 0; t < TT; t += 2) {
        STEP(t,     xA)
        STEP(t + 1, xB)
    }
    // final fast-weight step (D for t = TT-1)
    if (wv == 3) { PHASE_D(TT - 1) }
    (void)b;
}

// ---------------------------------------------------------------------------
// Kernel 3: out = h + O @ W_out^T   (M=32768, N=K=256), fp32.
// ---------------------------------------------------------------------------
#define GM 128
#define GN 64
#define GK 16

__global__ __launch_bounds__(256, 1) void out_proj_kernel(
    const float* __restrict__ O, const float* __restrict__ W,
    const float* __restrict__ hg, float* __restrict__ outg)
{
    __shared__ float As[GK][GM + 4];
    __shared__ float Bs[GK][GN + 4];
    const int tid = threadIdx.x;
    const int tx  = tid & 15;
    const int ty  = tid >> 4;
    const int r0  = blockIdx.x * GM;
    const int c0  = blockIdx.y * GN;

    float acc[8][4];
    #pragma unroll
    for (int i = 0; i < 8; i++)
        #pragma unroll
        for (int j = 0; j < 4; j++) acc[i][j] = 0.f;

    const int am  = tid >> 1;
    const int akg = (tid & 1) * 8;
    const int bn  = tid >> 2;
    const int bkg = (tid & 3) * 4;

    for (int k0 = 0; k0 < INN; k0 += GK) {
        float4 a0 = *(const float4*)(O + (size_t)(r0 + am) * INN + k0 + akg);
        float4 a1 = *(const float4*)(O + (size_t)(r0 + am) * INN + k0 + akg + 4);
        float4 w0 = *(const float4*)(W + (size_t)(c0 + bn) * INN + k0 + bkg);
        As[akg+0][am] = a0.x; As[akg+1][am] = a0.y; As[akg+2][am] = a0.z; As[akg+3][am] = a0.w;
        As[akg+4][am] = a1.x; As[akg+5][am] = a1.y; As[akg+6][am] = a1.z; As[akg+7][am] = a1.w;
        Bs[bkg+0][bn] = w0.x; Bs[bkg+1][bn] = w0.y;
        Bs[bkg+2][bn] = w0.z; Bs[bkg+3][bn] = w0.w;
        __syncthreads();
        #pragma unroll
        for (int k = 0; k < GK; k++) {
            float4 av0 = *(const float4*)&As[k][ty * 8];
            float4 av1 = *(const float4*)&As[k][ty * 8 + 4];
            float4 bv  = *(const float4*)&Bs[k][tx * 4];
            float a[8] = {av0.x, av0.y, av0.z, av0.w, av1.x, av1.y, av1.z, av1.w};
            float bb[4] = {bv.x, bv.y, bv.z, bv.w};
            #pragma unroll
            for (int i = 0; i < 8; i++)
                #pragma unroll
                for (int j = 0; j < 4; j++) acc[i][j] += a[i] * bb[j];
        }
        __syncthreads();
    }

    #pragma unroll
    for (int i = 0; i < 8; i++) {
        size_t r = (size_t)(r0 + ty * 8 + i);
        float4 hv = *(const float4*)(hg + r * INN + c0 + tx * 4);
        float4 o;
        o.x = hv.x + acc[i][0];
        o.y = hv.y + acc[i][1];
        o.z = hv.z + acc[i][2];
        o.w = hv.w + acc[i][3];
        *(float4*)(outg + r * INN + c0 + tx * 4) = o;
    }
}

// ---------------------------------------------------------------------------
extern "C" void kernel_launch(void* const* d_in, const int* in_sizes, int n_in,
                              void* d_out, int out_size, void* d_ws, size_t ws_size,
                              hipStream_t stream)
{
    (void)in_sizes; (void)n_in; (void)out_size; (void)ws_size;

    const float* hg   = (const float*)d_in[0];
    const float* Wy   = (const float*)d_in[1];
    const float* Wq   = (const float*)d_in[2];
    const float* Wk   = (const float*)d_in[3];
    const float* wb   = (const float*)d_in[4];
    const float* Wout = (const float*)d_in[5];
    const float* sWy  = (const float*)d_in[6];
    const float* sWq  = (const float*)d_in[7];
    const float* sWk  = (const float*)d_in[8];
    const float* swb  = (const float*)d_in[9];
    const float* Fw   = (const float*)d_in[10];
    float* out = (float*)d_out;

    float* xg = (float*)d_ws;                      // (T,B,H,D) fp32
    float* Og = xg + (size_t)TT * BB * INN;        // (T,B,IN)  fp32

    softmax_x_kernel<<<TT * BB * HH / 8, 256, 0, stream>>>(hg, xg);
    srwm_fwm_kernel<<<BB * HH, 256, 0, stream>>>(xg, Wy, Wq, Wk, wb,
                                                 sWy, sWq, sWk, swb, Fw, Og);
    out_proj_kernel<<<dim3(TT * BB / GM, INN / GN), 256, 0, stream>>>(Og, Wout, hg, out);
}

// Round 4
// 881.965 us; speedup vs baseline: 2.2165x; 1.2563x over previous
//
#include <hip/hip_runtime.h>
#include <cstdint>

#define TT  1024
#define BB  32
#define HH  8
#define DD  32
#define YDN 97
#define INN 256

typedef float v2f __attribute__((ext_vector_type(2)));
typedef float v4f __attribute__((ext_vector_type(4)));

// packed fp32 FMA (v_pk_fma_f32 on CDNA)
#define PK(acc, a, b) (acc) = __builtin_elementwise_fma((a), (b), (acc))

// LDS-only barrier: drains lgkmcnt, leaves global loads/stores in flight.
__device__ __forceinline__ void bar_lds() {
    asm volatile("s_waitcnt lgkmcnt(0)\n\ts_barrier" ::: "memory");
}

template<int C>
__device__ __forceinline__ float dppf(float x) {
    return __int_as_float(__builtin_amdgcn_update_dpp(
        0, __float_as_int(x), C, 0xF, 0xF, true));
}
__device__ __forceinline__ float swz16(float x) {
    return __int_as_float(__builtin_amdgcn_ds_swizzle(__float_as_int(x), 0x401F));
}
__device__ __forceinline__ float red_max32(float v) {
    v = fmaxf(v, dppf<0xB1>(v));
    v = fmaxf(v, dppf<0x4E>(v));
    v = fmaxf(v, dppf<0x141>(v));
    v = fmaxf(v, dppf<0x140>(v));
    v = fmaxf(v, swz16(v));
    return v;
}
__device__ __forceinline__ float red_sum32(float v) {
    v += dppf<0xB1>(v);
    v += dppf<0x4E>(v);
    v += dppf<0x141>(v);
    v += dppf<0x140>(v);
    v += swz16(v);
    return v;
}

// ---------------------------------------------------------------------------
// Kernel 1: x = softmax(h) over last dim (rows of 32)
// ---------------------------------------------------------------------------
__global__ __launch_bounds__(256, 1) void softmax_x_kernel(
    const float* __restrict__ hg, float* __restrict__ xg)
{
    const int row  = blockIdx.x * 8 + (threadIdx.x >> 5);
    const int lane = threadIdx.x & 31;
    float v = hg[(size_t)row * DD + lane];
    float m = red_max32(v);
    float ex = __expf(v - m);
    float sm = red_sum32(ex);
    xg[(size_t)row * DD + lane] = ex * __builtin_amdgcn_rcpf(sm);
}

// ---------------------------------------------------------------------------
// Kernel 2: recurrent SRWM + fast-weight memory. One block per (b,h).
// State rows in registers. Double-buffered LDS vectors -> ONE barrier/step.
// Wave roles: w0/w1: Wy+wb rows | w2: Wq,Wk rows + q/k exp (normalization
// deferred to consumers) | w3: fq/fk softmax + fast-weight memory (Phase D),
// fully overlapped with w0-2's B/C(t)+A(t+1).
// ---------------------------------------------------------------------------

#define STEP(T, XC, BUF)                                                      \
  {                                                                           \
    if (wv != 3 && mat >= 0) {                                                \
        v2f a0 = {0.f,0.f}, a1 = {0.f,0.f};                                   \
        _Pragma("unroll")                                                     \
        for (int g = 0; g < 8; g++) {                                         \
            PK(a0, XC[2*g],   row2[2*g]);                                     \
            PK(a1, XC[2*g+1], row2[2*g+1]);                                   \
        }                                                                     \
        v2f at = a0 + a1;                                                     \
        float pre = at.x + at.y;                                              \
        if (wv == 2) {                                                        \
            float m  = red_max32(pre);                                        \
            float ex = __expf(pre - m);                                       \
            if (lane < DD) exq_s[BUF][lane] = ex;                             \
            else           exk_s[BUF][lane - DD] = ex;                        \
            float sm = red_sum32(ex);                                         \
            float r  = __builtin_amdgcn_rcpf(sm);                             \
            if (lane == 0)  rr_s[BUF][0] = r;                                 \
            if (lane == DD) rr_s[BUF][1] = r;                                 \
        } else if (tid < YDN) {                                               \
            y_s[BUF][tid] = pre;                                              \
        } else {                                                              \
            beta_s[BUF][tid - YDN] =                                          \
                __builtin_amdgcn_rcpf(1.f + __expf(-pre));                    \
        }                                                                     \
    }                                                                         \
    bar_lds();                                                                \
    if (wv != 3) {                                                            \
        if ((T) + 2 < TT && mat >= 0) {   /* prefetch x(T+2) into XC */       \
            const v4f* p =                                                    \
                (const v4f*)(xg + ((size_t)((T)+2)*(BB*HH) + bh)*DD);         \
            _Pragma("unroll")                                                 \
            for (int g = 0; g < 8; g++) {                                     \
                v4f v = p[g];                                                 \
                XC[2*g]   = v.xy;                                             \
                XC[2*g+1] = v.zw;                                             \
            }                                                                 \
        }                                                                     \
        if (mat >= 0) {                                                       \
            const v2f* eq2 = (const v2f*)exq_s[BUF];                          \
            const v2f* ek2 = (const v2f*)exk_s[BUF];                          \
            v2f ekr[16];                                                      \
            _Pragma("unroll")                                                 \
            for (int g = 0; g < 16; g++) ekr[g] = ek2[g];                     \
            v2f q0={0.f,0.f}, q1={0.f,0.f}, k0={0.f,0.f}, k1={0.f,0.f};       \
            _Pragma("unroll")                                                 \
            for (int g = 0; g < 8; g++) {                                     \
                PK(q0, eq2[2*g],   row2[2*g]);                                \
                PK(q1, eq2[2*g+1], row2[2*g+1]);                              \
                PK(k0, ekr[2*g],   row2[2*g]);                                \
                PK(k1, ekr[2*g+1], row2[2*g+1]);                              \
            }                                                                 \
            v2f qt = q0 + q1, kt = k0 + k1;                                   \
            float dotq = qt.x + qt.y, dotk = kt.x + kt.y;                     \
            float rq = rr_s[BUF][0], rk = rr_s[BUF][1];                       \
            float bs = beta_s[BUF][mat] * (rq*dotq - rk*dotk) * rk;           \
            v2f bs2 = {bs, bs};                                               \
            _Pragma("unroll")                                                 \
            for (int g = 0; g < 16; g++) PK(row2[g], bs2, ekr[g]);            \
        }                                                                     \
    } else {                                                                  \
        float fpre = y_s[BUF][lane];                                          \
        float m  = red_max32(fpre);                                           \
        float ex = __expf(fpre - m);                                          \
        float sm = red_sum32(ex);                                             \
        float val = ex * __builtin_amdgcn_rcpf(sm);                           \
        if (lane < DD) fq_s[lane] = val;                                      \
        else           fk_s[lane - DD] = val;                                 \
        if (lane < DD) {                                                      \
            const v2f* fk2 = (const v2f*)fk_s;                                \
            const v2f* fq2 = (const v2f*)fq_s;                                \
            v2f fkr[16];                                                      \
            _Pragma("unroll")                                                 \
            for (int g = 0; g < 16; g++) fkr[g] = fk2[g];                     \
            v2f v0={0.f,0.f}, v1={0.f,0.f};                                   \
            _Pragma("unroll")                                                 \
            for (int g = 0; g < 8; g++) {                                     \
                PK(v0, fkr[2*g],   Frow2[2*g]);                               \
                PK(v1, fkr[2*g+1], Frow2[2*g+1]);                             \
            }                                                                 \
            v2f vt = v0 + v1;                                                 \
            float vold = vt.x + vt.y;                                         \
            float fb = __builtin_amdgcn_rcpf(1.f + __expf(-y_s[BUF][96]));    \
            float delta = fb * (y_s[BUF][64 + lane] - vold);                  \
            v2f d2 = {delta, delta};                                          \
            v2f o0={0.f,0.f}, o1={0.f,0.f};                                   \
            _Pragma("unroll")                                                 \
            for (int g = 0; g < 8; g++) {                                     \
                PK(Frow2[2*g],   d2, fkr[2*g]);                               \
                PK(o0, fq2[2*g],   Frow2[2*g]);                               \
                PK(Frow2[2*g+1], d2, fkr[2*g+1]);                             \
                PK(o1, fq2[2*g+1], Frow2[2*g+1]);                             \
            }                                                                 \
            v2f ot = o0 + o1;                                                 \
            Og[((size_t)(T) * (BB*HH) + bh) * DD + lane] = ot.x + ot.y;       \
        }                                                                     \
    }                                                                         \
  }

__global__ __launch_bounds__(256, 1) void srwm_fwm_kernel(
    const float* __restrict__ xg,
    const float* __restrict__ Wy_g, const float* __restrict__ Wq_g,
    const float* __restrict__ Wk_g, const float* __restrict__ wb_g,
    const float* __restrict__ sWy_g, const float* __restrict__ sWq_g,
    const float* __restrict__ sWk_g, const float* __restrict__ swb_g,
    const float* __restrict__ F_g,
    float* __restrict__ Og)
{
    const int bh   = blockIdx.x;
    const int hh   = bh & 7;
    const int tid  = threadIdx.x;
    const int wv   = tid >> 6;
    const int lane = tid & 63;

    __shared__ __align__(16) float y_s[2][104];
    __shared__ __align__(16) float exq_s[2][DD];
    __shared__ __align__(16) float exk_s[2][DD];
    __shared__ __align__(16) float beta_s[2][4];
    __shared__ __align__(16) float rr_s[2][2];
    __shared__ __align__(16) float fq_s[DD];
    __shared__ __align__(16) float fk_s[DD];

    v2f row2[16];    // SRWM state row (waves 0-2)
    v2f Frow2[16];   // fast-weight row (wave 3, lanes 0-31)
    v2f xA2[16], xB2[16];

    int e = -1, mat = -1;
    if (tid < 97)                     { e = tid;       mat = 0; }
    else if (tid < 101)               { e = tid - 97;  mat = 3; }
    else if (tid >= 128 && tid < 160) { e = tid - 128; mat = 1; }
    else if (tid >= 160 && tid < 192) { e = tid - 160; mat = 2; }

    // ---- init state rows: row = (W + state)^T column e ----
    {
        const float* wp = nullptr; const float* sp = nullptr; int str = 0;
        if (mat == 0) {
            wp = Wy_g  + (size_t)hh * DD * YDN + e;
            sp = sWy_g + (size_t)bh * DD * YDN + e;  str = YDN;
        } else if (mat == 1) {
            wp = Wq_g  + (size_t)hh * DD * DD + e;
            sp = sWq_g + (size_t)bh * DD * DD + e;   str = DD;
        } else if (mat == 2) {
            wp = Wk_g  + (size_t)hh * DD * DD + e;
            sp = sWk_g + (size_t)bh * DD * DD + e;   str = DD;
        } else if (mat == 3) {
            wp = wb_g  + (size_t)hh * DD * 4 + e;
            sp = swb_g + (size_t)bh * DD * 4 + e;    str = 4;
        }
        if (mat >= 0) {
            #pragma unroll
            for (int d = 0; d < 16; d++) {
                v2f t;
                t.x = wp[(2*d)   * str] + sp[(2*d)   * str];
                t.y = wp[(2*d+1) * str] + sp[(2*d+1) * str];
                row2[d] = t;
            }
        }
    }
    if (wv == 3 && lane < DD) {      // F^T rows
        const float* fp = F_g + (size_t)bh * DD * DD + lane;
        #pragma unroll
        for (int d = 0; d < 16; d++) {
            v2f t;
            t.x = fp[(2*d)   * DD];
            t.y = fp[(2*d+1) * DD];
            Frow2[d] = t;
        }
    }

    // x(0), x(1)
    if (mat >= 0) {
        const v4f* p0 = (const v4f*)(xg + (size_t)bh * DD);
        const v4f* p1 = (const v4f*)(xg + ((size_t)(BB*HH) + bh) * DD);
        #pragma unroll
        for (int g = 0; g < 8; g++) {
            v4f a = p0[g]; v4f b = p1[g];
            xA2[2*g] = a.xy; xA2[2*g+1] = a.zw;
            xB2[2*g] = b.xy; xB2[2*g+1] = b.zw;
        }
    }

    for (int t = 0; t < TT; t += 2) {
        STEP(t,     xA2, 0)
        STEP(t + 1, xB2, 1)
    }
}

// ---------------------------------------------------------------------------
// Kernel 3: out = h + O @ W_out^T   (M=32768, N=K=256), fp32.
// ---------------------------------------------------------------------------
#define GM 128
#define GN 64
#define GK 16

__global__ __launch_bounds__(256, 1) void out_proj_kernel(
    const float* __restrict__ O, const float* __restrict__ W,
    const float* __restrict__ hg, float* __restrict__ outg)
{
    __shared__ float As[GK][GM + 4];
    __shared__ float Bs[GK][GN + 4];
    const int tid = threadIdx.x;
    const int tx  = tid & 15;
    const int ty  = tid >> 4;
    const int r0  = blockIdx.x * GM;
    const int c0  = blockIdx.y * GN;

    float acc[8][4];
    #pragma unroll
    for (int i = 0; i < 8; i++)
        #pragma unroll
        for (int j = 0; j < 4; j++) acc[i][j] = 0.f;

    const int am  = tid >> 1;
    const int akg = (tid & 1) * 8;
    const int bn  = tid >> 2;
    const int bkg = (tid & 3) * 4;

    for (int k0 = 0; k0 < INN; k0 += GK) {
        float4 a0 = *(const float4*)(O + (size_t)(r0 + am) * INN + k0 + akg);
        float4 a1 = *(const float4*)(O + (size_t)(r0 + am) * INN + k0 + akg + 4);
        float4 w0 = *(const float4*)(W + (size_t)(c0 + bn) * INN + k0 + bkg);
        As[akg+0][am] = a0.x; As[akg+1][am] = a0.y; As[akg+2][am] = a0.z; As[akg+3][am] = a0.w;
        As[akg+4][am] = a1.x; As[akg+5][am] = a1.y; As[akg+6][am] = a1.z; As[akg+7][am] = a1.w;
        Bs[bkg+0][bn] = w0.x; Bs[bkg+1][bn] = w0.y;
        Bs[bkg+2][bn] = w0.z; Bs[bkg+3][bn] = w0.w;
        __syncthreads();
        #pragma unroll
        for (int k = 0; k < GK; k++) {
            float4 av0 = *(const float4*)&As[k][ty * 8];
            float4 av1 = *(const float4*)&As[k][ty * 8 + 4];
            float4 bv  = *(const float4*)&Bs[k][tx * 4];
            float a[8] = {av0.x, av0.y, av0.z, av0.w, av1.x, av1.y, av1.z, av1.w};
            float bb[4] = {bv.x, bv.y, bv.z, bv.w};
            #pragma unroll
            for (int i = 0; i < 8; i++)
                #pragma unroll
                for (int j = 0; j < 4; j++) acc[i][j] += a[i] * bb[j];
        }
        __syncthreads();
    }

    #pragma unroll
    for (int i = 0; i < 8; i++) {
        size_t r = (size_t)(r0 + ty * 8 + i);
        float4 hv = *(const float4*)(hg + r * INN + c0 + tx * 4);
        float4 o;
        o.x = hv.x + acc[i][0];
        o.y = hv.y + acc[i][1];
        o.z = hv.z + acc[i][2];
        o.w = hv.w + acc[i][3];
        *(float4*)(outg + r * INN + c0 + tx * 4) = o;
    }
}

// ---------------------------------------------------------------------------
extern "C" void kernel_launch(void* const* d_in, const int* in_sizes, int n_in,
                              void* d_out, int out_size, void* d_ws, size_t ws_size,
                              hipStream_t stream)
{
    (void)in_sizes; (void)n_in; (void)out_size; (void)ws_size;

    const float* hg   = (const float*)d_in[0];
    const float* Wy   = (const float*)d_in[1];
    const float* Wq   = (const float*)d_in[2];
    const float* Wk   = (const float*)d_in[3];
    const float* wb   = (const float*)d_in[4];
    const float* Wout = (const float*)d_in[5];
    const float* sWy  = (const float*)d_in[6];
    const float* sWq  = (const float*)d_in[7];
    const float* sWk  = (const float*)d_in[8];
    const float* swb  = (const float*)d_in[9];
    const float* Fw   = (const float*)d_in[10];
    float* out = (float*)d_out;

    float* xg = (float*)d_ws;                      // (T,B,H,D) fp32
    float* Og = xg + (size_t)TT * BB * INN;        // (T,B,IN)  fp32

    softmax_x_kernel<<<TT * BB * HH / 8, 256, 0, stream>>>(hg, xg);
    srwm_fwm_kernel<<<BB * HH, 256, 0, stream>>>(xg, Wy, Wq, Wk, wb,
                                                 sWy, sWq, sWk, swb, Fw, Og);
    out_proj_kernel<<<dim3(TT * BB / GM, INN / GN), 256, 0, stream>>>(Og, Wout, hg, out);
}

// Round 5
// 821.263 us; speedup vs baseline: 2.3803x; 1.0739x over previous
//
#include <hip/hip_runtime.h>
#include <cstdint>

#define TT  1024
#define BB  32
#define HH  8
#define DD  32
#define YDN 97
#define INN 256

typedef float v2f __attribute__((ext_vector_type(2)));
typedef float v4f __attribute__((ext_vector_type(4)));

// packed fp32 FMA (v_pk_fma_f32 on CDNA)
#define PK(acc, a, b) (acc) = __builtin_elementwise_fma((a), (b), (acc))

// LDS-only barrier: drains lgkmcnt, leaves global loads/stores in flight.
__device__ __forceinline__ void bar_lds() {
    asm volatile("s_waitcnt lgkmcnt(0)\n\ts_barrier" ::: "memory");
}

template<int C>
__device__ __forceinline__ float dppf(float x) {
    return __int_as_float(__builtin_amdgcn_update_dpp(
        0, __float_as_int(x), C, 0xF, 0xF, true));
}
__device__ __forceinline__ float swz16(float x) {
    return __int_as_float(__builtin_amdgcn_ds_swizzle(__float_as_int(x), 0x401F));
}
__device__ __forceinline__ float red_max32(float v) {
    v = fmaxf(v, dppf<0xB1>(v));
    v = fmaxf(v, dppf<0x4E>(v));
    v = fmaxf(v, dppf<0x141>(v));
    v = fmaxf(v, dppf<0x140>(v));
    v = fmaxf(v, swz16(v));
    return v;
}
__device__ __forceinline__ float red_sum32(float v) {
    v += dppf<0xB1>(v);
    v += dppf<0x4E>(v);
    v += dppf<0x141>(v);
    v += dppf<0x140>(v);
    v += swz16(v);
    return v;
}

// exp with overflow guard (values are O(1); clamp never binds in practice)
__device__ __forceinline__ float cexp(float v) {
    return __expf(fminf(v, 60.f));
}

// ---------------------------------------------------------------------------
// Kernel 1: x = softmax(h) over last dim (rows of 32)
// ---------------------------------------------------------------------------
__global__ __launch_bounds__(256, 1) void softmax_x_kernel(
    const float* __restrict__ hg, float* __restrict__ xg)
{
    const int row  = blockIdx.x * 8 + (threadIdx.x >> 5);
    const int lane = threadIdx.x & 31;
    float v = hg[(size_t)row * DD + lane];
    float m = red_max32(v);
    float ex = __expf(v - m);
    float sm = red_sum32(ex);
    xg[(size_t)row * DD + lane] = ex * __builtin_amdgcn_rcpf(sm);
}

// ---------------------------------------------------------------------------
// Kernel 2: recurrent SRWM + fast-weight memory. One block per (b,h).
// State rows in registers. ONE barrier/step. Software-pipelined wave roles:
//   region1(t): w0/w1/w2 Phase A (dot + exp, no-max softmax, deferred norm)
//               w3: Phase D(t-1)  [overlaps A]
//   barrier
//   region2(t): w0/w1/w2: B/C rank-1 update (+x(t+2) prefetch)
//               w3: fq/fk exp+sum from y(t), capture fv/fb/rcp in regs
// ---------------------------------------------------------------------------

// Phase D for step TP (wave 3, lanes 0-31). Uses fq_s/fk_s (same-wave LDS),
// regs fv_r, fb_r, rqf, rkf captured in region2(TP).
#define PHASE_D(TP)                                                           \
    if (lane < DD) {                                                          \
        const v2f* fk2 = (const v2f*)fk_s;                                    \
        const v2f* fq2 = (const v2f*)fq_s;                                    \
        v2f fkr[16];                                                          \
        _Pragma("unroll")                                                     \
        for (int g = 0; g < 16; g++) fkr[g] = fk2[g];                         \
        v2f v0={0.f,0.f}, v1={0.f,0.f};                                       \
        _Pragma("unroll")                                                     \
        for (int g = 0; g < 8; g++) {                                         \
            PK(v0, fkr[2*g],   Frow2[2*g]);                                   \
            PK(v1, fkr[2*g+1], Frow2[2*g+1]);                                 \
        }                                                                     \
        v2f vt = v0 + v1;                                                     \
        float vold = rkf * (vt.x + vt.y);                                     \
        float d2s  = fb_r * (fv_r - vold) * rkf;                              \
        v2f d2 = {d2s, d2s};                                                  \
        v2f o0={0.f,0.f}, o1={0.f,0.f};                                       \
        _Pragma("unroll")                                                     \
        for (int g = 0; g < 8; g++) {                                         \
            PK(Frow2[2*g],   d2, fkr[2*g]);                                   \
            PK(o0, fq2[2*g],   Frow2[2*g]);                                   \
            PK(Frow2[2*g+1], d2, fkr[2*g+1]);                                 \
            PK(o1, fq2[2*g+1], Frow2[2*g+1]);                                 \
        }                                                                     \
        v2f ot = o0 + o1;                                                     \
        Og[((size_t)(TP) * (BB*HH) + bh) * DD + lane] =                       \
            rqf * (ot.x + ot.y);                                              \
    }

#define STEP(T, XC, BUF)                                                      \
  {                                                                           \
    /* ---------------- region 1 ---------------- */                          \
    if (wv == 3) {                                                            \
        if ((T) > 0) { PHASE_D((T)-1) }                                       \
    } else if (mat >= 0) {                                                    \
        v2f a0 = {0.f,0.f}, a1 = {0.f,0.f};                                   \
        _Pragma("unroll")                                                     \
        for (int g = 0; g < 8; g++) {                                         \
            PK(a0, XC[2*g],   row2[2*g]);                                     \
            PK(a1, XC[2*g+1], row2[2*g+1]);                                   \
        }                                                                     \
        v2f at = a0 + a1;                                                     \
        float pre = at.x + at.y;                                              \
        if (wv == 2) {                                                        \
            float ex = cexp(pre);                                             \
            if (lane < DD) exq_s[BUF][lane]      = ex;                        \
            else           exk_s[BUF][lane - DD] = ex;                        \
            float sm = red_sum32(ex);                                         \
            float r  = __builtin_amdgcn_rcpf(sm);                             \
            if (lane == 0)       rr_s[BUF][0] = r;                            \
            else if (lane == DD) rr_s[BUF][1] = r;                            \
        } else if (tid < YDN) {                                               \
            y_s[BUF][tid] = pre;                                              \
        } else {                                                              \
            beta_s[BUF][tid - YDN] =                                          \
                __builtin_amdgcn_rcpf(1.f + __expf(-pre));                    \
        }                                                                     \
    }                                                                         \
    bar_lds();                                                                \
    /* ---------------- region 2 ---------------- */                          \
    if (wv != 3) {                                                            \
        if ((T) + 2 < TT && mat >= 0) {   /* prefetch x(T+2) into XC */       \
            const v4f* p =                                                    \
                (const v4f*)(xg + ((size_t)((T)+2)*(BB*HH) + bh)*DD);         \
            _Pragma("unroll")                                                 \
            for (int g = 0; g < 8; g++) {                                     \
                v4f v = p[g];                                                 \
                XC[2*g]   = v.xy;                                             \
                XC[2*g+1] = v.zw;                                             \
            }                                                                 \
        }                                                                     \
        if (mat >= 0) {                                                       \
            const v2f* eq2 = (const v2f*)exq_s[BUF];                          \
            const v2f* ek2 = (const v2f*)exk_s[BUF];                          \
            v2f ekr[16];                                                      \
            _Pragma("unroll")                                                 \
            for (int g = 0; g < 16; g++) ekr[g] = ek2[g];                     \
            v2f q0={0.f,0.f}, q1={0.f,0.f}, k0={0.f,0.f}, k1={0.f,0.f};       \
            _Pragma("unroll")                                                 \
            for (int g = 0; g < 8; g++) {                                     \
                PK(q0, eq2[2*g],   row2[2*g]);                                \
                PK(q1, eq2[2*g+1], row2[2*g+1]);                              \
                PK(k0, ekr[2*g],   row2[2*g]);                                \
                PK(k1, ekr[2*g+1], row2[2*g+1]);                              \
            }                                                                 \
            v2f qt = q0 + q1, kt = k0 + k1;                                   \
            float dotq = qt.x + qt.y, dotk = kt.x + kt.y;                     \
            v2f rr = *(const v2f*)rr_s[BUF];                                  \
            float bs = beta_s[BUF][mat] * (rr.x*dotq - rr.y*dotk) * rr.y;     \
            v2f bs2 = {bs, bs};                                               \
            _Pragma("unroll")                                                 \
            for (int g = 0; g < 16; g++) PK(row2[g], bs2, ekr[g]);            \
        }                                                                     \
    } else {                                                                  \
        /* fq/fk exp+sum (no-max, deferred norm); capture state for D(T) */   \
        float fpre = y_s[BUF][lane];                                          \
        float ex = cexp(fpre);                                                \
        if (lane < DD) fq_s[lane]      = ex;                                  \
        else           fk_s[lane - DD] = ex;                                  \
        float sm = red_sum32(ex);                                             \
        float r  = __builtin_amdgcn_rcpf(sm);                                 \
        float rO = __shfl_xor(r, 32, 64);                                     \
        rqf = (lane < DD) ? r : rO;                                           \
        rkf = (lane < DD) ? rO : r;                                           \
        fv_r = y_s[BUF][64 + (lane & 31)];                                    \
        fb_r = __builtin_amdgcn_rcpf(1.f + __expf(-y_s[BUF][96]));            \
    }                                                                         \
  }

__global__ __launch_bounds__(256, 1) void srwm_fwm_kernel(
    const float* __restrict__ xg,
    const float* __restrict__ Wy_g, const float* __restrict__ Wq_g,
    const float* __restrict__ Wk_g, const float* __restrict__ wb_g,
    const float* __restrict__ sWy_g, const float* __restrict__ sWq_g,
    const float* __restrict__ sWk_g, const float* __restrict__ swb_g,
    const float* __restrict__ F_g,
    float* __restrict__ Og)
{
    const int bh   = blockIdx.x;
    const int hh   = bh & 7;
    const int tid  = threadIdx.x;
    const int wv   = tid >> 6;
    const int lane = tid & 63;

    __shared__ __align__(16) float y_s[2][104];
    __shared__ __align__(16) float exq_s[2][DD];
    __shared__ __align__(16) float exk_s[2][DD];
    __shared__ __align__(16) float beta_s[2][4];
    __shared__ __align__(16) float rr_s[2][2];
    __shared__ __align__(16) float fq_s[DD];
    __shared__ __align__(16) float fk_s[DD];

    v2f row2[16];    // SRWM state row (waves 0-2)
    v2f Frow2[16];   // fast-weight row (wave 3, lanes 0-31)
    v2f xA2[16], xB2[16];
    float fv_r = 0.f, fb_r = 0.f, rqf = 0.f, rkf = 0.f;

    int e = -1, mat = -1;
    if (tid < 97)                     { e = tid;       mat = 0; }
    else if (tid < 101)               { e = tid - 97;  mat = 3; }
    else if (tid >= 128 && tid < 160) { e = tid - 128; mat = 1; }
    else if (tid >= 160 && tid < 192) { e = tid - 160; mat = 2; }

    // ---- init state rows: row = (W + state)^T column e ----
    {
        const float* wp = nullptr; const float* sp = nullptr; int str = 0;
        if (mat == 0) {
            wp = Wy_g  + (size_t)hh * DD * YDN + e;
            sp = sWy_g + (size_t)bh * DD * YDN + e;  str = YDN;
        } else if (mat == 1) {
            wp = Wq_g  + (size_t)hh * DD * DD + e;
            sp = sWq_g + (size_t)bh * DD * DD + e;   str = DD;
        } else if (mat == 2) {
            wp = Wk_g  + (size_t)hh * DD * DD + e;
            sp = sWk_g + (size_t)bh * DD * DD + e;   str = DD;
        } else if (mat == 3) {
            wp = wb_g  + (size_t)hh * DD * 4 + e;
            sp = swb_g + (size_t)bh * DD * 4 + e;    str = 4;
        }
        if (mat >= 0) {
            #pragma unroll
            for (int d = 0; d < 16; d++) {
                v2f t;
                t.x = wp[(2*d)   * str] + sp[(2*d)   * str];
                t.y = wp[(2*d+1) * str] + sp[(2*d+1) * str];
                row2[d] = t;
            }
        }
    }
    if (wv == 3 && lane < DD) {      // F^T rows (lane e holds F[:,e])
        const float* fp = F_g + (size_t)bh * DD * DD + lane;
        #pragma unroll
        for (int d = 0; d < 16; d++) {
            v2f t;
            t.x = fp[(2*d)   * DD];
            t.y = fp[(2*d+1) * DD];
            Frow2[d] = t;
        }
    }

    // x(0), x(1)
    if (mat >= 0) {
        const v4f* p0 = (const v4f*)(xg + (size_t)bh * DD);
        const v4f* p1 = (const v4f*)(xg + ((size_t)(BB*HH) + bh) * DD);
        #pragma unroll
        for (int g = 0; g < 8; g++) {
            v4f a = p0[g]; v4f b = p1[g];
            xA2[2*g] = a.xy; xA2[2*g+1] = a.zw;
            xB2[2*g] = b.xy; xB2[2*g+1] = b.zw;
        }
    }

    for (int t = 0; t < TT; t += 2) {
        STEP(t,     xA2, 0)
        STEP(t + 1, xB2, 1)
    }
    // drain the pipeline: Phase D for t = TT-1
    if (wv == 3) { PHASE_D(TT - 1) }
}

// ---------------------------------------------------------------------------
// Kernel 3: out = h + O @ W_out^T   (M=32768, N=K=256), fp32.
// ---------------------------------------------------------------------------
#define GM 128
#define GN 64
#define GK 16

__global__ __launch_bounds__(256, 1) void out_proj_kernel(
    const float* __restrict__ O, const float* __restrict__ W,
    const float* __restrict__ hg, float* __restrict__ outg)
{
    __shared__ float As[GK][GM + 4];
    __shared__ float Bs[GK][GN + 4];
    const int tid = threadIdx.x;
    const int tx  = tid & 15;
    const int ty  = tid >> 4;
    const int r0  = blockIdx.x * GM;
    const int c0  = blockIdx.y * GN;

    float acc[8][4];
    #pragma unroll
    for (int i = 0; i < 8; i++)
        #pragma unroll
        for (int j = 0; j < 4; j++) acc[i][j] = 0.f;

    const int am  = tid >> 1;
    const int akg = (tid & 1) * 8;
    const int bn  = tid >> 2;
    const int bkg = (tid & 3) * 4;

    for (int k0 = 0; k0 < INN; k0 += GK) {
        float4 a0 = *(const float4*)(O + (size_t)(r0 + am) * INN + k0 + akg);
        float4 a1 = *(const float4*)(O + (size_t)(r0 + am) * INN + k0 + akg + 4);
        float4 w0 = *(const float4*)(W + (size_t)(c0 + bn) * INN + k0 + bkg);
        As[akg+0][am] = a0.x; As[akg+1][am] = a0.y; As[akg+2][am] = a0.z; As[akg+3][am] = a0.w;
        As[akg+4][am] = a1.x; As[akg+5][am] = a1.y; As[akg+6][am] = a1.z; As[akg+7][am] = a1.w;
        Bs[bkg+0][bn] = w0.x; Bs[bkg+1][bn] = w0.y;
        Bs[bkg+2][bn] = w0.z; Bs[bkg+3][bn] = w0.w;
        __syncthreads();
        #pragma unroll
        for (int k = 0; k < GK; k++) {
            float4 av0 = *(const float4*)&As[k][ty * 8];
            float4 av1 = *(const float4*)&As[k][ty * 8 + 4];
            float4 bv  = *(const float4*)&Bs[k][tx * 4];
            float a[8] = {av0.x, av0.y, av0.z, av0.w, av1.x, av1.y, av1.z, av1.w};
            float bb[4] = {bv.x, bv.y, bv.z, bv.w};
            #pragma unroll
            for (int i = 0; i < 8; i++)
                #pragma unroll
                for (int j = 0; j < 4; j++) acc[i][j] += a[i] * bb[j];
        }
        __syncthreads();
    }

    #pragma unroll
    for (int i = 0; i < 8; i++) {
        size_t r = (size_t)(r0 + ty * 8 + i);
        float4 hv = *(const float4*)(hg + r * INN + c0 + tx * 4);
        float4 o;
        o.x = hv.x + acc[i][0];
        o.y = hv.y + acc[i][1];
        o.z = hv.z + acc[i][2];
        o.w = hv.w + acc[i][3];
        *(float4*)(outg + r * INN + c0 + tx * 4) = o;
    }
}

// ---------------------------------------------------------------------------
extern "C" void kernel_launch(void* const* d_in, const int* in_sizes, int n_in,
                              void* d_out, int out_size, void* d_ws, size_t ws_size,
                              hipStream_t stream)
{
    (void)in_sizes; (void)n_in; (void)out_size; (void)ws_size;

    const float* hg   = (const float*)d_in[0];
    const float* Wy   = (const float*)d_in[1];
    const float* Wq   = (const float*)d_in[2];
    const float* Wk   = (const float*)d_in[3];
    const float* wb   = (const float*)d_in[4];
    const float* Wout = (const float*)d_in[5];
    const float* sWy  = (const float*)d_in[6];
    const float* sWq  = (const float*)d_in[7];
    const float* sWk  = (const float*)d_in[8];
    const float* swb  = (const float*)d_in[9];
    const float* Fw   = (const float*)d_in[10];
    float* out = (float*)d_out;

    float* xg = (float*)d_ws;                      // (T,B,H,D) fp32
    float* Og = xg + (size_t)TT * BB * INN;        // (T,B,IN)  fp32

    softmax_x_kernel<<<TT * BB * HH / 8, 256, 0, stream>>>(hg, xg);
    srwm_fwm_kernel<<<BB * HH, 256, 0, stream>>>(xg, Wy, Wq, Wk, wb,
                                                 sWy, sWq, sWk, swb, Fw, Og);
    out_proj_kernel<<<dim3(TT * BB / GM, INN / GN), 256, 0, stream>>>(Og, Wout, hg, out);
}